// Round 6
// baseline (141.333 us; speedup 1.0000x reference)
//
#include <hip/hip_runtime.h>

#define FG 15
#define NPROP 512
#define NCLS 16
#define NCI 30   // B*FG
#define SCORE_T 0.05f
#define NMS_T 0.5f
#define DETS 100
#define STAGE_CAP 4096  // per-block pair staging (expected ~300-600/block)

typedef unsigned long long u64;
typedef unsigned int u32;

__device__ __forceinline__ unsigned sortable_f32(float f) {
  unsigned u = __float_as_uint(f);
  return u ^ ((u >> 31) ? 0xFFFFFFFFu : 0x80000000u);
}

// ---------------- register Sutherland-Hodgman (fast-math; IoU slack >> rounding) --------
#define CLIP_EMIT(V, VALIDEXPR, CX, CY, NX, NY)                                \
  {                                                                            \
    bool valid = (VALIDEXPR);                                                  \
    float cx = (CX), cy = (CY), nx = (NX), ny = (NY);                          \
    float sc = ex * (cy - p1y) - ey * (cx - p1x);                              \
    float sn = ex * (ny - p1y) - ey * (nx - p1x);                              \
    bool ic = sc >= 0.f, inn = sn >= 0.f;                                      \
    float den = sc - sn;                                                       \
    float dsel = (fabsf(den) > 1e-8f) ? den : 1.f;                             \
    float tt = sc * __builtin_amdgcn_rcpf(dsel);                               \
    float qx = cx + tt * (nx - cx);                                            \
    float qy = cy + tt * (ny - cy);                                            \
    bool fC = valid && ic;                                                     \
    bool fI = valid && (ic != inn);                                            \
    _Pragma("unroll") for (int o = 0; o < 8; ++o) if (o <= 2 * (V)) {          \
      bool wr = fC && (m == o);                                                \
      ox[o] = wr ? cx : ox[o];                                                 \
      oy[o] = wr ? cy : oy[o];                                                 \
    }                                                                          \
    m += fC ? 1 : 0;                                                           \
    _Pragma("unroll") for (int o = 0; o < 8; ++o) if (o <= 2 * (V) + 1) {      \
      bool wr = fI && (m == o);                                                \
      ox[o] = wr ? qx : ox[o];                                                 \
      oy[o] = wr ? qy : oy[o];                                                 \
    }                                                                          \
    m += fI ? 1 : 0;                                                           \
  }

__device__ __forceinline__ float inter_area_fast(const float (&Ax)[4], const float (&Ay)[4],
                                                 const float (&Bx)[4], const float (&By)[4]) {
  float inx[8], iny[8];
  int n = 4;
#pragma unroll
  for (int v = 0; v < 4; ++v) {
    inx[v] = Ax[v]; iny[v] = Ay[v];
    inx[v + 4] = 0.f; iny[v + 4] = 0.f;
  }
#pragma unroll
  for (int e = 0; e < 4; ++e) {
    int e2 = (e + 1) & 3;
    float p1x = Bx[e], p1y = By[e];
    float ex = Bx[e2] - p1x, ey = By[e2] - p1y;
    float ox[8], oy[8];
    int m = 0;
#pragma unroll
    for (int o = 0; o < 8; ++o) { ox[o] = 0.f; oy[o] = 0.f; }
    if (e == 0) {  // n == 4 statically
#pragma unroll
      for (int v = 0; v < 4; ++v) {
        CLIP_EMIT(v, true, inx[v], iny[v], inx[(v + 1) & 3], iny[(v + 1) & 3]);
      }
    } else {
#pragma unroll
      for (int v = 0; v < 8; ++v) {
        bool wrap = (v + 1 >= n);
        CLIP_EMIT(v, v < n, inx[v], iny[v],
                  wrap ? inx[0] : inx[(v + 1) & 7],
                  wrap ? iny[0] : iny[(v + 1) & 7]);
      }
    }
    n = (m < 8) ? m : 8;
#pragma unroll
    for (int o = 0; o < 8; ++o) { inx[o] = ox[o]; iny[o] = oy[o]; }
  }
  float s = 0.f;
#pragma unroll
  for (int v = 0; v < 8; ++v) {
    bool valid = v < n;
    bool wrap = (v + 1 >= n);
    float axx = inx[v], ayy = iny[v];
    float bxx = wrap ? inx[0] : inx[(v + 1) & 7];
    float byy = wrap ? iny[0] : iny[(v + 1) & 7];
    float cr = axx * byy - bxx * ayy;
    s += valid ? cr : 0.f;
  }
  float area = 0.5f * fabsf(s);
  return (n >= 3) ? area : 0.f;
}

// ---------------- kernel 1: entire per-class pipeline in one block ----------------
// decode+softmax -> bitonic sort -> corners -> circle filter -> clip -> greedy NMS.
// All intermediates (scores, corners, pair list, 512x512-bit mask) LDS-resident.
__global__ void __launch_bounds__(512) k_main(
    const float* __restrict__ logits, const float* __restrict__ regr,
    const float* __restrict__ prop,
    float* __restrict__ bsort,    // [NCI][NPROP][5] sorted boxes (for k_topk gather)
    u64* __restrict__ kkey) {     // [NCI][128] kept keys, desc, 0-filled
  int ci = blockIdx.x;
  int b = ci / FG;
  int c = ci - b * FG + 1;  // class 1..15
  int tid = threadIdx.x;
  int lane = tid & 63;

  __shared__ float scs[NPROP];        // unsorted scores        2 KB
  __shared__ float bb_s[5][NPROP];    // unsorted boxes        10 KB
  __shared__ u64 key[NPROP];          // sort keys              4 KB
  __shared__ float ssl[NPROP];        // sorted masked scores   2 KB
  __shared__ float4 prc4[NPROP];      // (x,y,r,area) sorted    8 KB
  __shared__ float crn[NPROP][8];     // sorted corners        16 KB
  __shared__ u32 stage[STAGE_CAP];    // pair staging          16 KB
  __shared__ u64 maskl[NPROP * 8];    // suppression bitmask   32 KB
  __shared__ u64 keptw[8];
  __shared__ int wpre[8];
  __shared__ int vloc, lcnt;

  if (tid == 0) { vloc = NPROP; lcnt = 0; }
  for (int x = tid; x < NPROP * 8; x += 512) maskl[x] = 0ull;
  if (tid < 8) keptw[tid] = 0ull;

  // ---- decode + softmax (bit-identical to reference path) ----
  {
#pragma clang fp contract(off)
    int n = tid;  // 512 threads == NPROP
    int g = b * NPROP + n;
    const float* lg = logits + g * NCLS;
    float l[NCLS];
    float mx = -INFINITY;
#pragma unroll
    for (int q = 0; q < NCLS; ++q) { l[q] = lg[q]; mx = fmaxf(mx, l[q]); }
    float sum = 0.f, ec = 0.f;
#pragma unroll
    for (int q = 0; q < NCLS; ++q) {
      float e = expf(l[q] - mx);
      sum += e;
      if (q == c) ec = e;
    }
    float sc = ec / sum;
    scs[n] = sc;
    const float* pb = prop + g * 5;
    float xc = pb[0], yc = pb[1], w = pb[2], h = pb[3], a = pb[4];
    const float* r = regr + g * 80 + c * 5;
    float dx = r[0] / 10.0f;
    float dy = r[1] / 10.0f;
    float dw = fminf(r[2] / 5.0f, 4.135166556742356f);
    float dh = fminf(r[3] / 5.0f, 4.135166556742356f);
    float da = r[4] / 10.0f;
    bb_s[0][n] = dx * w + xc;
    bb_s[1][n] = dy * h + yc;
    bb_s[2][n] = expf(dw) * w;
    bb_s[3][n] = expf(dh) * h;
    bb_s[4][n] = da * 57.29577951308232f + a;
    float m = (sc > SCORE_T) ? sc : -INFINITY;
    unsigned so = sortable_f32(m);
    key[n] = ((u64)(~so) << 32) | (unsigned)n;  // asc key = desc score, asc idx
  }
  __syncthreads();

  // ---- bitonic sort 512 keys (256 active compare threads) ----
  for (int k = 2; k <= NPROP; k <<= 1) {
    for (int j = k >> 1; j > 0; j >>= 1) {
      if (tid < 256) {
        int t = tid;
        int i1 = ((t & ~(j - 1)) << 1) | (t & (j - 1));
        int i2 = i1 | j;
        bool up = ((i1 & k) == 0);
        u64 a = key[i1], cc = key[i2];
        bool sw = up ? (a > cc) : (a < cc);
        if (sw) { key[i1] = cc; key[i2] = a; }
      }
      __syncthreads();
    }
  }

  // ---- gather sorted, corners + circle params (exact mk_corners path) ----
  {
#pragma clang fp contract(off)
    int i = tid;
    u64 kv = key[i];
    int idx = (int)(kv & 0xFFFFFFFFull);
    float v = scs[idx];
    float sv = (v > SCORE_T) ? v : -INFINITY;
    ssl[i] = sv;
    if (!(sv > SCORE_T)) atomicMin(&vloc, i);
    float bb[5];
#pragma unroll
    for (int q = 0; q < 5; ++q) bb[q] = bb_s[q][idx];
    float* dst = bsort + ((size_t)ci * NPROP + i) * 5;
#pragma unroll
    for (int q = 0; q < 5; ++q) dst[q] = bb[q];
    float t = bb[4] * 0.017453292519943295f;
    float cs = cosf(t), sn = sinf(t);
    float hw = bb[2] * 0.5f, hh = bb[3] * 0.5f;
    float lx[4] = {-hw, hw, hw, -hw};
    float ly[4] = {-hh, -hh, hh, hh};
#pragma unroll
    for (int k = 0; k < 4; ++k) {
      crn[i][k]     = bb[0] + lx[k] * cs - ly[k] * sn;
      crn[i][4 + k] = bb[1] + lx[k] * sn + ly[k] * cs;
    }
    float rr = 0.5f * sqrtf(bb[2] * bb[2] + bb[3] * bb[3]);
    prc4[i] = make_float4(bb[0], bb[1], rr, bb[2] * bb[3]);
  }
  __syncthreads();
  int V = vloc;

  // ---- phase 1: circle test, stage surviving pairs in LDS ----
  for (int i = 0; i < V; ++i) {
    float4 pi = prc4[i];
    bool pass = false;
    if (tid > i && tid < V) {
      float4 pj = prc4[tid];
      float dx = pi.x - pj.x, dy = pi.y - pj.y;
      float rs = pi.z + pj.z;
      pass = (dx * dx + dy * dy) <= rs * rs;
    }
    u64 bal = __ballot(pass);
    if (bal) {
      int base = 0;
      if (lane == 0) base = atomicAdd(&lcnt, (int)__popcll(bal));
      base = __shfl(base, 0);
      if (pass) {
        int pos = base + (int)__popcll(bal & ((1ull << lane) - 1ull));
        if (pos < STAGE_CAP) stage[pos] = ((u32)i << 9) | (u32)tid;
      }
    }
  }
  __syncthreads();
  int tot = lcnt < STAGE_CAP ? lcnt : STAGE_CAP;

  // ---- phase 2: clip staged pairs (corners from LDS), set mask bits ----
  for (int p = tid; p < tot; p += 512) {
    u32 w = stage[p];
    int i = w >> 9, j = w & 511;
    float4 a0 = *(const float4*)&crn[i][0];
    float4 a1 = *(const float4*)&crn[i][4];
    float4 b0 = *(const float4*)&crn[j][0];
    float4 b1 = *(const float4*)&crn[j][4];
    float Ax[4] = {a0.x, a0.y, a0.z, a0.w};
    float Ay[4] = {a1.x, a1.y, a1.z, a1.w};
    float Bx[4] = {b0.x, b0.y, b0.z, b0.w};
    float By[4] = {b1.x, b1.y, b1.z, b1.w};
    float inter = inter_area_fast(Ax, Ay, Bx, By);
    float areaA = prc4[i].w;
    float areaB = prc4[j].w;
    float uni = (areaA + areaB) - inter;
    float iou = inter / fmaxf(uni, 1e-8f);
    if (iou > NMS_T)
      atomicOr(&maskl[i * 8 + (j >> 6)], 1ull << (j & 63));
  }
  __syncthreads();

  // ---- greedy bitmask NMS scan (single wave) ----
  if (tid < 64) {
    u64 removed = 0ull, kb = 0ull;
    int kc = 0;
    for (int i = 0; i < V; ++i) {
      int w = i >> 6, bp = i & 63;
      u64 rw = __shfl(removed, w);
      if (!((rw >> bp) & 1ull)) {
        if (lane == w) kb |= (1ull << bp);
        if (lane < 8) removed |= maskl[i * 8 + lane];
        if (++kc >= DETS) break;  // first 100 kept fully determine output
      }
    }
    if (lane < 8) keptw[lane] = kb;
  }
  __syncthreads();
  if (tid == 0) {
    int acc = 0;
#pragma unroll
    for (int w = 0; w < 8; ++w) { wpre[w] = acc; acc += (int)__popcll(keptw[w]); }
  }
  __syncthreads();
  {
    int i = tid;
    int cfg = c - 1;
    u64 kw = keptw[i >> 6];
    if ((kw >> (i & 63)) & 1ull) {
      int rank = wpre[i >> 6] + (int)__popcll(kw & ((1ull << (i & 63)) - 1ull));
      float s = ssl[i];
      u32 hi = __float_as_uint(s) ^ 0x80000000u;  // s > 0.05 > 0
      u32 flat = (u32)(cfg * NPROP + i);
      kkey[ci * 128 + rank] = ((u64)hi << 32) | (u32)(~flat);  // ties: lower flat wins max
    }
    int total = wpre[7] + (int)__popcll(keptw[7]);
    if (i < 128 && i >= total) kkey[ci * 128 + i] = 0ull;
  }
}

// ---------------- kernel 2: parallel rank-select top-100 ----------------
// All real keys are strictly distinct (flat idx embedded), so output slot of a
// key == its exact rank = #keys greater, summed over the 15 desc-sorted lists
// via branchless binary search. Unique ranks => collision-free scatter.
__global__ void __launch_bounds__(1024) k_topk(
    const u64* __restrict__ kkey,
    const float* __restrict__ bsort,
    float* __restrict__ out) {
  int b = blockIdx.x;  // 2 blocks, 1024 threads
  __shared__ u64 lk[FG * 128];  // 15 KiB
  __shared__ u64 res[DETS];
  for (int x = threadIdx.x; x < FG * 128; x += 1024) lk[x] = kkey[b * FG * 128 + x];
  for (int x = threadIdx.x; x < DETS; x += 1024) res[x] = 0ull;
  __syncthreads();
  for (int x = threadIdx.x; x < FG * 128; x += 1024) {
    u64 key = lk[x];
    if (key == 0ull) continue;  // real keys have hi bit set (score > 0)
    int rank = 0;
#pragma unroll
    for (int c = 0; c < FG; ++c) {
      const u64* a = &lk[c * 128];
      int pos = 0;
#pragma unroll
      for (int st = 64; st > 0; st >>= 1)
        pos += (a[pos + st - 1] > key) ? st : 0;  // pos in [0,127]
      rank += pos + ((a[pos] > key) ? 1 : 0);
    }
    if (rank < DETS) res[rank] = key;
  }
  __syncthreads();
  if (threadIdx.x < DETS) {
    u64 key = res[threadIdx.x];
    float* o = out + ((size_t)b * DETS + threadIdx.x) * 6;
    if (key == 0ull) {
#pragma unroll
      for (int q = 0; q < 6; ++q) o[q] = 0.f;
    } else {
      u32 flat = ~(u32)(key & 0xFFFFFFFFull);
      int cfg = flat >> 9, pos = flat & 511;
      const float* bx = bsort + (((size_t)b * FG + cfg) * NPROP + pos) * 5;
#pragma unroll
      for (int q = 0; q < 5; ++q) o[q] = bx[q];
      o[5] = __uint_as_float((u32)(key >> 32) ^ 0x80000000u);
    }
  }
}

extern "C" void kernel_launch(void* const* d_in, const int* in_sizes, int n_in,
                              void* d_out, int out_size, void* d_ws, size_t ws_size,
                              hipStream_t stream) {
  const float* logits = (const float*)d_in[0];
  const float* regr   = (const float*)d_in[1];
  const float* prop   = (const float*)d_in[2];
  float* out = (float*)d_out;

  float* bsort = (float*)d_ws;              // NCI*NPROP*5 floats
  u64* kkey    = (u64*)(bsort + NCI * NPROP * 5);  // NCI*128 u64 (8B-aligned: 307200 B offset)

  hipLaunchKernelGGL(k_main, dim3(NCI), dim3(512), 0, stream,
                     logits, regr, prop, bsort, kkey);
  hipLaunchKernelGGL(k_topk, dim3(2), dim3(1024), 0, stream, kkey, bsort, out);
}

// Round 7
// 62.164 us; speedup vs baseline: 2.2736x; 2.2736x over previous
//
#include <hip/hip_runtime.h>

#define FG 15
#define NPROP 512
#define NCLS 16
#define NCI 30   // B*FG
#define SCORE_T 0.05f
#define NMS_T 0.5f
#define DETS 100
#define STRIPES 8
#define STAGE_CAP 4096  // per-stripe-block pair staging (expected ~300/block)

typedef unsigned long long u64;
typedef unsigned int u32;

__device__ __forceinline__ unsigned sortable_f32(float f) {
  unsigned u = __float_as_uint(f);
  return u ^ ((u >> 31) ? 0xFFFFFFFFu : 0x80000000u);
}

// ---------------- kernel 1: decode+softmax + rank-sort (1 barrier) ----------------
// Keys strictly distinct (idx in low bits) => rank = #smaller keys is a
// permutation => collision-free scatter. Identical ordering to the previous
// ascending bitonic sort.
__global__ void __launch_bounds__(512) k_sortdec(
    const float* __restrict__ logits, const float* __restrict__ regr,
    const float* __restrict__ prop,
    float* __restrict__ ssort,    // [NCI][NPROP] masked scores, sorted desc
    float* __restrict__ bsort) {  // [NCI][NPROP][5] sorted boxes
  int ci = blockIdx.x;
  int b = ci / FG;
  int c = ci - b * FG + 1;  // class 1..15
  int tid = threadIdx.x;    // == proposal index n
  __shared__ __align__(16) u64 key[NPROP];

  float sc, bb[5];
  {
#pragma clang fp contract(off)
    int g = b * NPROP + tid;
    const float* lg = logits + g * NCLS;
    float l[NCLS];
    float mx = -INFINITY;
#pragma unroll
    for (int q = 0; q < NCLS; ++q) { l[q] = lg[q]; mx = fmaxf(mx, l[q]); }
    float sum = 0.f, ec = 0.f;
#pragma unroll
    for (int q = 0; q < NCLS; ++q) {
      float e = expf(l[q] - mx);
      sum += e;
      if (q == c) ec = e;
    }
    sc = ec / sum;  // bit-identical to reference path
    const float* pb = prop + g * 5;
    float xc = pb[0], yc = pb[1], w = pb[2], h = pb[3], a = pb[4];
    const float* r = regr + g * 80 + c * 5;
    float dx = r[0] / 10.0f;
    float dy = r[1] / 10.0f;
    float dw = fminf(r[2] / 5.0f, 4.135166556742356f);
    float dh = fminf(r[3] / 5.0f, 4.135166556742356f);
    float da = r[4] / 10.0f;
    bb[0] = dx * w + xc;
    bb[1] = dy * h + yc;
    bb[2] = expf(dw) * w;
    bb[3] = expf(dh) * h;
    bb[4] = da * 57.29577951308232f + a;
    float m = (sc > SCORE_T) ? sc : -INFINITY;
    key[tid] = ((u64)(~sortable_f32(m)) << 32) | (u32)tid;  // asc key = desc score, asc idx
  }
  __syncthreads();
  u64 myk = key[tid];
  int rank = 0;
  const ulonglong2* k2 = (const ulonglong2*)key;
#pragma unroll 4
  for (int m = 0; m < NPROP / 2; ++m) {
    ulonglong2 kk = k2[m];  // ds_read_b128 broadcast
    rank += (kk.x < myk) ? 1 : 0;
    rank += (kk.y < myk) ? 1 : 0;
  }
  ssort[ci * NPROP + rank] = (sc > SCORE_T) ? sc : -INFINITY;
  float* dst = bsort + ((size_t)ci * NPROP + rank) * 5;
#pragma unroll
  for (int q = 0; q < 5; ++q) dst[q] = bb[q];
}

// ---------------- register Sutherland-Hodgman (fast-math; IoU slack >> rounding) --------
#define CLIP_EMIT(V, VALIDEXPR, CX, CY, NX, NY)                                \
  {                                                                            \
    bool valid = (VALIDEXPR);                                                  \
    float cx = (CX), cy = (CY), nx = (NX), ny = (NY);                          \
    float sc = ex * (cy - p1y) - ey * (cx - p1x);                              \
    float sn = ex * (ny - p1y) - ey * (nx - p1x);                              \
    bool ic = sc >= 0.f, inn = sn >= 0.f;                                      \
    float den = sc - sn;                                                       \
    float dsel = (fabsf(den) > 1e-8f) ? den : 1.f;                             \
    float tt = sc * __builtin_amdgcn_rcpf(dsel);                               \
    float qx = cx + tt * (nx - cx);                                            \
    float qy = cy + tt * (ny - cy);                                            \
    bool fC = valid && ic;                                                     \
    bool fI = valid && (ic != inn);                                            \
    _Pragma("unroll") for (int o = 0; o < 8; ++o) if (o <= 2 * (V)) {          \
      bool wr = fC && (m == o);                                                \
      ox[o] = wr ? cx : ox[o];                                                 \
      oy[o] = wr ? cy : oy[o];                                                 \
    }                                                                          \
    m += fC ? 1 : 0;                                                           \
    _Pragma("unroll") for (int o = 0; o < 8; ++o) if (o <= 2 * (V) + 1) {      \
      bool wr = fI && (m == o);                                                \
      ox[o] = wr ? qx : ox[o];                                                 \
      oy[o] = wr ? qy : oy[o];                                                 \
    }                                                                          \
    m += fI ? 1 : 0;                                                           \
  }

__device__ __forceinline__ float inter_area_fast(const float (&Ax)[4], const float (&Ay)[4],
                                                 const float (&Bx)[4], const float (&By)[4]) {
  float inx[8], iny[8];
  int n = 4;
#pragma unroll
  for (int v = 0; v < 4; ++v) {
    inx[v] = Ax[v]; iny[v] = Ay[v];
    inx[v + 4] = 0.f; iny[v + 4] = 0.f;
  }
#pragma unroll
  for (int e = 0; e < 4; ++e) {
    int e2 = (e + 1) & 3;
    float p1x = Bx[e], p1y = By[e];
    float ex = Bx[e2] - p1x, ey = By[e2] - p1y;
    float ox[8], oy[8];
    int m = 0;
#pragma unroll
    for (int o = 0; o < 8; ++o) { ox[o] = 0.f; oy[o] = 0.f; }
    if (e == 0) {  // n == 4 statically
#pragma unroll
      for (int v = 0; v < 4; ++v) {
        CLIP_EMIT(v, true, inx[v], iny[v], inx[(v + 1) & 3], iny[(v + 1) & 3]);
      }
    } else {
#pragma unroll
      for (int v = 0; v < 8; ++v) {
        bool wrap = (v + 1 >= n);
        CLIP_EMIT(v, v < n, inx[v], iny[v],
                  wrap ? inx[0] : inx[(v + 1) & 7],
                  wrap ? iny[0] : iny[(v + 1) & 7]);
      }
    }
    n = (m < 8) ? m : 8;
#pragma unroll
    for (int o = 0; o < 8; ++o) { inx[o] = ox[o]; iny[o] = oy[o]; }
  }
  float s = 0.f;
#pragma unroll
  for (int v = 0; v < 8; ++v) {
    bool valid = v < n;
    bool wrap = (v + 1 >= n);
    float axx = inx[v], ayy = iny[v];
    float bxx = wrap ? inx[0] : inx[(v + 1) & 7];
    float byy = wrap ? iny[0] : iny[(v + 1) & 7];
    float cr = axx * byy - bxx * ayy;
    s += valid ? cr : 0.f;
  }
  float area = 0.5f * fabsf(s);
  return (n >= 3) ? area : 0.f;
}

// ---------------- kernel 2: fused circle-filter + clip (striped) ----------------
// Block (ci, s) owns rows i == s (mod 8): zeroes exactly those mask rows, then
// atomicOrs only into them (disjoint across blocks). Corners/areas recomputed
// from bsort with the exact contract-off expressions (bitwise identical).
__global__ void __launch_bounds__(512) k_paircl(
    const float* __restrict__ ssort, const float* __restrict__ bsort,
    u64* __restrict__ mask) {
  int ci = blockIdx.x;
  int s = blockIdx.y;
  int tid = threadIdx.x;
  int lane = tid & 63;
  __shared__ float4 prc4[NPROP];                  // (x,y,r,area)  8 KB
  __shared__ __align__(16) float crn[NPROP][8];   // corners      16 KB
  __shared__ u32 stage[STAGE_CAP];                // pair staging 16 KB
  __shared__ int vloc, lcnt;
  const float* ss = ssort + ci * NPROP;
  if (tid == 0) { vloc = NPROP; lcnt = 0; }
  __syncthreads();
  if (!(ss[tid] > SCORE_T)) atomicMin(&vloc, tid);
  {
#pragma clang fp contract(off)
    const float* bp_ = bsort + ((size_t)ci * NPROP + tid) * 5;
    float b0 = bp_[0], b1 = bp_[1], b2 = bp_[2], b3 = bp_[3], b4 = bp_[4];
    float t = b4 * 0.017453292519943295f;
    float cs = cosf(t), sn = sinf(t);
    float hw = b2 * 0.5f, hh = b3 * 0.5f;
    float lx[4] = {-hw, hw, hw, -hw};
    float ly[4] = {-hh, -hh, hh, hh};
#pragma unroll
    for (int k = 0; k < 4; ++k) {
      crn[tid][k]     = b0 + lx[k] * cs - ly[k] * sn;
      crn[tid][4 + k] = b1 + lx[k] * sn + ly[k] * cs;
    }
    prc4[tid] = make_float4(b0, b1, 0.5f * sqrtf(b2 * b2 + b3 * b3), b2 * b3);
  }
  // zero this block's own mask rows: row = s + 8*(tid>>3), word = tid&7
  mask[((size_t)ci * NPROP + s + 8 * (tid >> 3)) * 8 + (tid & 7)] = 0ull;
  __syncthreads();
  int V = vloc;
  // phase 1: circle test, stage surviving pairs in LDS
  for (int i = s; i < V; i += STRIPES) {
    float4 pi = prc4[i];
    bool pass = false;
    if (tid > i && tid < V) {
      float4 pj = prc4[tid];
      float dx = pi.x - pj.x, dy = pi.y - pj.y;
      float rs = pi.z + pj.z;
      pass = (dx * dx + dy * dy) <= rs * rs;  // disjoint circles => inter == 0
    }
    u64 bal = __ballot(pass);
    if (bal) {
      int base = 0;
      if (lane == 0) base = atomicAdd(&lcnt, (int)__popcll(bal));
      base = __shfl(base, 0);
      if (pass) {
        int pos = base + (int)__popcll(bal & ((1ull << lane) - 1ull));
        if (pos < STAGE_CAP) stage[pos] = ((u32)i << 9) | (u32)tid;
      }
    }
  }
  __syncthreads();
  int tot = lcnt < STAGE_CAP ? lcnt : STAGE_CAP;
  // phase 2: clip staged pairs (corners from LDS), set own mask rows
  for (int p = tid; p < tot; p += 512) {
    u32 w = stage[p];
    int i = w >> 9, j = w & 511;
    float4 a0 = *(const float4*)&crn[i][0];
    float4 a1 = *(const float4*)&crn[i][4];
    float4 b0 = *(const float4*)&crn[j][0];
    float4 b1 = *(const float4*)&crn[j][4];
    float Ax[4] = {a0.x, a0.y, a0.z, a0.w};
    float Ay[4] = {a1.x, a1.y, a1.z, a1.w};
    float Bx[4] = {b0.x, b0.y, b0.z, b0.w};
    float By[4] = {b1.x, b1.y, b1.z, b1.w};
    float inter = inter_area_fast(Ax, Ay, Bx, By);
    float areaA = prc4[i].w;
    float areaB = prc4[j].w;
    float uni = (areaA + areaB) - inter;
    float iou = inter / fmaxf(uni, 1e-8f);
    if (iou > NMS_T)
      atomicOr(&mask[((size_t)ci * NPROP + i) * 8 + (j >> 6)], 1ull << (j & 63));
  }
}

// ---------------- kernel 3: greedy NMS scan (register-resident, prefetched) ----------------
__global__ void __launch_bounds__(256) k_nms(
    const float* __restrict__ ssort, const u64* __restrict__ mask,
    u64* __restrict__ kkey) {  // [NCI][128] sortable keys, desc, 0-filled
  int ci = blockIdx.x;
  int b = ci / FG, cfg = ci - b * FG;
  __shared__ u64 lmask[(NPROP + 4) * 8];  // 33 KB (+4 pad rows for prefetch)
  __shared__ u64 keptw[8];
  __shared__ int vcnt;
  __shared__ int wpre[8];
  int tid = threadIdx.x;
  const float* ss = ssort + ci * NPROP;
  if (tid == 0) vcnt = NPROP;
  __syncthreads();
  for (int i = tid; i < NPROP; i += 256)
    if (!(ss[i] > SCORE_T)) atomicMin(&vcnt, i);
  __syncthreads();
  int V = vcnt;
  for (int x = tid; x < V * 8; x += 256)
    lmask[x] = mask[(size_t)ci * NPROP * 8 + x];
  if (tid < 32) lmask[V * 8 + tid] = 0ull;  // pad rows V..V+3
  __syncthreads();
  // single-thread scan; rem/kept/buf all statically indexed (stay in VGPRs),
  // 4-deep ping-pong prefetch hides LDS latency on the dependent chain.
  if (tid == 0) {
    u64 rem[8] = {0, 0, 0, 0, 0, 0, 0, 0};
    u64 kept[8] = {0, 0, 0, 0, 0, 0, 0, 0};
    u64 buf[4][8];
#pragma unroll
    for (int d = 0; d < 4; ++d)
#pragma unroll
      for (int w = 0; w < 8; ++w) buf[d][w] = lmask[d * 8 + w];
    int kc = 0;
    bool stop = (V == 0);
#pragma unroll
    for (int w8 = 0; w8 < 8; ++w8) {
      int lim = V - (w8 << 6);
      lim = lim > 64 ? 64 : lim;
      if (!stop && lim > 0) {
        int lim4 = (lim + 3) & ~3;
        for (int bp4 = 0; bp4 < lim4 && !stop; bp4 += 4) {
#pragma unroll
          for (int d = 0; d < 4; ++d) {
            int bp = bp4 + d;
            int i = (w8 << 6) | bp;
            if (bp < lim && !stop) {
              if (!((rem[w8] >> bp) & 1ull)) {
                kept[w8] |= 1ull << bp;
#pragma unroll
                for (int w = 0; w < 8; ++w) rem[w] |= buf[d][w];
                if (++kc >= DETS) stop = true;  // first 100 kept determine output
              }
            }
#pragma unroll
            for (int w = 0; w < 8; ++w) buf[d][w] = lmask[(i + 4) * 8 + w];  // prefetch
          }
        }
      }
    }
#pragma unroll
    for (int w = 0; w < 8; ++w) keptw[w] = kept[w];
  }
  __syncthreads();
  if (tid == 0) {
    int acc = 0;
#pragma unroll
    for (int w = 0; w < 8; ++w) { wpre[w] = acc; acc += (int)__popcll(keptw[w]); }
  }
  __syncthreads();
  for (int i = tid; i < NPROP; i += 256) {
    u64 kw = keptw[i >> 6];
    if ((kw >> (i & 63)) & 1ull) {
      int rank = wpre[i >> 6] + (int)__popcll(kw & ((1ull << (i & 63)) - 1ull));
      float s = ss[i];
      u32 hi = __float_as_uint(s) ^ 0x80000000u;  // s > 0.05 > 0
      u32 flat = (u32)(cfg * NPROP + i);
      kkey[ci * 128 + rank] = ((u64)hi << 32) | (u32)(~flat);  // ties: lower flat wins max
    }
  }
  int total = wpre[7] + (int)__popcll(keptw[7]);
  for (int r = tid; r < 128; r += 256)
    if (r >= total) kkey[ci * 128 + r] = 0ull;
}

// ---------------- kernel 4: parallel rank-select top-100 ----------------
__global__ void __launch_bounds__(1024) k_topk(
    const u64* __restrict__ kkey,
    const float* __restrict__ bsort,
    float* __restrict__ out) {
  int b = blockIdx.x;  // 2 blocks, 1024 threads
  __shared__ u64 lk[FG * 128];  // 15 KiB
  __shared__ u64 res[DETS];
  for (int x = threadIdx.x; x < FG * 128; x += 1024) lk[x] = kkey[b * FG * 128 + x];
  for (int x = threadIdx.x; x < DETS; x += 1024) res[x] = 0ull;
  __syncthreads();
  for (int x = threadIdx.x; x < FG * 128; x += 1024) {
    u64 key = lk[x];
    if (key == 0ull) continue;  // real keys have hi bit set (score > 0)
    int rank = 0;
#pragma unroll
    for (int c = 0; c < FG; ++c) {
      const u64* a = &lk[c * 128];
      int pos = 0;
#pragma unroll
      for (int st = 64; st > 0; st >>= 1)
        pos += (a[pos + st - 1] > key) ? st : 0;  // pos in [0,127]
      rank += pos + ((a[pos] > key) ? 1 : 0);
    }
    if (rank < DETS) res[rank] = key;
  }
  __syncthreads();
  if (threadIdx.x < DETS) {
    u64 key = res[threadIdx.x];
    float* o = out + ((size_t)b * DETS + threadIdx.x) * 6;
    if (key == 0ull) {
#pragma unroll
      for (int q = 0; q < 6; ++q) o[q] = 0.f;
    } else {
      u32 flat = ~(u32)(key & 0xFFFFFFFFull);
      int cfg = flat >> 9, pos = flat & 511;
      const float* bx = bsort + (((size_t)b * FG + cfg) * NPROP + pos) * 5;
#pragma unroll
      for (int q = 0; q < 5; ++q) o[q] = bx[q];
      o[5] = __uint_as_float((u32)(key >> 32) ^ 0x80000000u);
    }
  }
}

extern "C" void kernel_launch(void* const* d_in, const int* in_sizes, int n_in,
                              void* d_out, int out_size, void* d_ws, size_t ws_size,
                              hipStream_t stream) {
  const float* logits = (const float*)d_in[0];
  const float* regr   = (const float*)d_in[1];
  const float* prop   = (const float*)d_in[2];
  float* out = (float*)d_out;

  float* ssort = (float*)d_ws;                     // 15360 f
  float* bsort = ssort + NCI * NPROP;              // 76800 f
  u64* kkey    = (u64*)(bsort + NCI * NPROP * 5);  // 3840 u64 (368640 B offset, 8B-aligned)
  u64* mask    = kkey + NCI * 128;                 // 122880 u64 (~1.4 MB total)

  hipLaunchKernelGGL(k_sortdec, dim3(NCI), dim3(512), 0, stream,
                     logits, regr, prop, ssort, bsort);
  hipLaunchKernelGGL(k_paircl, dim3(NCI, STRIPES), dim3(512), 0, stream,
                     ssort, bsort, mask);
  hipLaunchKernelGGL(k_nms, dim3(NCI), dim3(256), 0, stream, ssort, mask, kkey);
  hipLaunchKernelGGL(k_topk, dim3(2), dim3(1024), 0, stream, kkey, bsort, out);
}